// Round 1
// baseline (621.594 us; speedup 1.0000x reference)
//
#include <hip/hip_runtime.h>

// SpikingSelfAttention: pool8 -> W_qkv GEMM -> spike -> attn (no softmax, use
// M = V*K^T trick) -> W_out GEMM -> BN -> spike -> repeat8.
// All fp32 (spike thresholds are exact-sensitive; bf16 MFMA deferred).

#define SPIKE_THRESH 2.0f   // x/TAU >= VTH  <=>  x >= 2.0
#define BN_EPS 1e-5f

// ---------------- Kernel A: avg-pool 8 along T ----------------
// x: (32,512,4096) f32 -> xp: (32,512,512) f32
__global__ __launch_bounds__(256) void pool_kernel(const float* __restrict__ x,
                                                   float* __restrict__ xp, int n) {
  for (int i = blockIdx.x * blockDim.x + threadIdx.x; i < n;
       i += gridDim.x * blockDim.x) {
    const float4* p = reinterpret_cast<const float4*>(x) + (size_t)i * 2;
    float4 a = p[0], b = p[1];
    xp[i] = (((a.x + a.y) + (a.z + a.w)) + ((b.x + b.y) + (b.z + b.w))) * 0.125f;
  }
}

// ---------------- Kernel B: QKV GEMM + spike ----------------
// qkv[b,o,t] = spike( sum_c W[o,c] * xp[b,c,t] ),  W: (1536,512)
// 64x64 tile, 256 threads, 4x4 micro-tile, BK=16.
__global__ __launch_bounds__(256) void qkv_gemm_spike(const float* __restrict__ W,
                                                      const float* __restrict__ xp,
                                                      float* __restrict__ qkv) {
  const int b = blockIdx.z;
  const int oT = blockIdx.y * 64;
  const int tT = blockIdx.x * 64;
  const float* X = xp + (size_t)b * 512 * 512;
  float* out = qkv + (size_t)b * 1536 * 512;

  __shared__ float As[16][64];  // As[k][o]
  __shared__ float Bs[16][64];  // Bs[k][t]

  const int tid = threadIdx.x;
  const int tx = tid & 15, ty = tid >> 4;
  const int a_o = tid >> 2, a_k = (tid & 3) << 2;  // 64 rows x 16 k
  const int b_k = tid >> 4, b_t = (tid & 15) << 2; // 16 rows x 64 t

  float acc[4][4] = {};

  for (int k0 = 0; k0 < 512; k0 += 16) {
    float4 av = *reinterpret_cast<const float4*>(W + (size_t)(oT + a_o) * 512 + k0 + a_k);
    float4 bv = *reinterpret_cast<const float4*>(X + (size_t)(k0 + b_k) * 512 + tT + b_t);
    __syncthreads();
    As[a_k + 0][a_o] = av.x;
    As[a_k + 1][a_o] = av.y;
    As[a_k + 2][a_o] = av.z;
    As[a_k + 3][a_o] = av.w;
    *reinterpret_cast<float4*>(&Bs[b_k][b_t]) = bv;
    __syncthreads();
#pragma unroll
    for (int kk = 0; kk < 16; ++kk) {
      float4 a = *reinterpret_cast<const float4*>(&As[kk][ty << 2]);
      float4 bb = *reinterpret_cast<const float4*>(&Bs[kk][tx << 2]);
      float ar[4] = {a.x, a.y, a.z, a.w};
      float br[4] = {bb.x, bb.y, bb.z, bb.w};
#pragma unroll
      for (int i = 0; i < 4; ++i)
#pragma unroll
        for (int j = 0; j < 4; ++j) acc[i][j] += ar[i] * br[j];
    }
  }
#pragma unroll
  for (int i = 0; i < 4; ++i) {
    const int o = oT + (ty << 2) + i;
#pragma unroll
    for (int j = 0; j < 4; ++j) {
      const int t = tT + (tx << 2) + j;
      out[(size_t)o * 512 + t] = (acc[i][j] >= SPIKE_THRESH) ? 1.0f : 0.0f;
    }
  }
}

// ---------------- Kernel C: attention via M = V K^T, out = scale * M Q -----
// One block per (b,h). q,k,v are rows of qkv: o = g*512 + h*64 + d.
__global__ __launch_bounds__(256) void attn_kernel(const float* __restrict__ qkv,
                                                   float* __restrict__ att) {
  const int b = blockIdx.x >> 3;
  const int h = blockIdx.x & 7;
  const float* Q = qkv + (size_t)b * 1536 * 512 + (size_t)(h * 64) * 512;
  const float* K = qkv + (size_t)b * 1536 * 512 + (size_t)(512 + h * 64) * 512;
  const float* V = qkv + (size_t)b * 1536 * 512 + (size_t)(1024 + h * 64) * 512;
  float* O = att + (size_t)b * 512 * 512 + (size_t)(h * 64) * 512;

  __shared__ float Vs[16][64];   // Vs[s][d]
  __shared__ float Ks[16][64];   // Ks[s][e]
  __shared__ float Ms[64][64];   // Ms[e][d]  (transposed for phase 2)
  __shared__ float Qs[64][64];   // Qs[e][t]

  const int tid = threadIdx.x;
  const int tx = tid & 15, ty = tid >> 4;
  const int l_r = tid >> 2, l_c = (tid & 3) << 2;

  // Phase 1: M[d,e] = sum_s V[d,s] * K[e,s]
  float m[4][4] = {};
  for (int s0 = 0; s0 < 512; s0 += 16) {
    float4 vv = *reinterpret_cast<const float4*>(V + (size_t)l_r * 512 + s0 + l_c);
    float4 kv = *reinterpret_cast<const float4*>(K + (size_t)l_r * 512 + s0 + l_c);
    __syncthreads();
    Vs[l_c + 0][l_r] = vv.x; Vs[l_c + 1][l_r] = vv.y;
    Vs[l_c + 2][l_r] = vv.z; Vs[l_c + 3][l_r] = vv.w;
    Ks[l_c + 0][l_r] = kv.x; Ks[l_c + 1][l_r] = kv.y;
    Ks[l_c + 2][l_r] = kv.z; Ks[l_c + 3][l_r] = kv.w;
    __syncthreads();
#pragma unroll
    for (int ss = 0; ss < 16; ++ss) {
      float4 vd = *reinterpret_cast<const float4*>(&Vs[ss][ty << 2]);
      float4 ke = *reinterpret_cast<const float4*>(&Ks[ss][tx << 2]);
      float vr[4] = {vd.x, vd.y, vd.z, vd.w};
      float kr[4] = {ke.x, ke.y, ke.z, ke.w};
#pragma unroll
      for (int i = 0; i < 4; ++i)
#pragma unroll
        for (int j = 0; j < 4; ++j) m[i][j] += vr[i] * kr[j];
    }
  }
  __syncthreads();
#pragma unroll
  for (int i = 0; i < 4; ++i)
#pragma unroll
    for (int j = 0; j < 4; ++j) Ms[(tx << 2) + j][(ty << 2) + i] = m[i][j];
  __syncthreads();

  // Phase 2: O[d, t] = 0.125 * sum_e Ms[e][d] * Q[e][t]
  for (int tt = 0; tt < 512; tt += 64) {
#pragma unroll
    for (int r = 0; r < 4; ++r) {
      const int e = (tid >> 4) + r * 16;
      const int c = (tid & 15) << 2;
      *reinterpret_cast<float4*>(&Qs[e][c]) =
          *reinterpret_cast<const float4*>(Q + (size_t)e * 512 + tt + c);
    }
    __syncthreads();
    float acc[4][4] = {};
#pragma unroll
    for (int e = 0; e < 64; ++e) {
      float4 md = *reinterpret_cast<const float4*>(&Ms[e][ty << 2]);
      float4 qt = *reinterpret_cast<const float4*>(&Qs[e][tx << 2]);
      float mr[4] = {md.x, md.y, md.z, md.w};
      float qr[4] = {qt.x, qt.y, qt.z, qt.w};
#pragma unroll
      for (int i = 0; i < 4; ++i)
#pragma unroll
        for (int j = 0; j < 4; ++j) acc[i][j] += mr[i] * qr[j];
    }
#pragma unroll
    for (int i = 0; i < 4; ++i)
#pragma unroll
      for (int j = 0; j < 4; ++j)
        O[(size_t)((ty << 2) + i) * 512 + tt + (tx << 2) + j] = acc[i][j] * 0.125f;
    __syncthreads();
  }
}

// ---------------- Kernel D: W_out GEMM + BN + spike + repeat8 ----------------
__global__ __launch_bounds__(256) void out_gemm_bn_spike(
    const float* __restrict__ W, const float* __restrict__ att,
    const float* __restrict__ gamma, const float* __restrict__ beta,
    const float* __restrict__ mean, const float* __restrict__ var,
    float* __restrict__ out) {
  const int b = blockIdx.z;
  const int oT = blockIdx.y * 64;
  const int tT = blockIdx.x * 64;
  const float* X = att + (size_t)b * 512 * 512;

  __shared__ float As[16][64];
  __shared__ float Bs[16][64];

  const int tid = threadIdx.x;
  const int tx = tid & 15, ty = tid >> 4;
  const int a_o = tid >> 2, a_k = (tid & 3) << 2;
  const int b_k = tid >> 4, b_t = (tid & 15) << 2;

  float acc[4][4] = {};

  for (int k0 = 0; k0 < 512; k0 += 16) {
    float4 av = *reinterpret_cast<const float4*>(W + (size_t)(oT + a_o) * 512 + k0 + a_k);
    float4 bv = *reinterpret_cast<const float4*>(X + (size_t)(k0 + b_k) * 512 + tT + b_t);
    __syncthreads();
    As[a_k + 0][a_o] = av.x;
    As[a_k + 1][a_o] = av.y;
    As[a_k + 2][a_o] = av.z;
    As[a_k + 3][a_o] = av.w;
    *reinterpret_cast<float4*>(&Bs[b_k][b_t]) = bv;
    __syncthreads();
#pragma unroll
    for (int kk = 0; kk < 16; ++kk) {
      float4 a = *reinterpret_cast<const float4*>(&As[kk][ty << 2]);
      float4 bb = *reinterpret_cast<const float4*>(&Bs[kk][tx << 2]);
      float ar[4] = {a.x, a.y, a.z, a.w};
      float br[4] = {bb.x, bb.y, bb.z, bb.w};
#pragma unroll
      for (int i = 0; i < 4; ++i)
#pragma unroll
        for (int j = 0; j < 4; ++j) acc[i][j] += ar[i] * br[j];
    }
  }
#pragma unroll
  for (int i = 0; i < 4; ++i) {
    const int o = oT + (ty << 2) + i;
    const float inv = gamma[o] / sqrtf(var[o] + BN_EPS);
    const float bias = beta[o] - mean[o] * inv;
    float* dst = out + ((size_t)b * 512 + o) * 4096 + (size_t)(tT + (tx << 2)) * 8;
#pragma unroll
    for (int j = 0; j < 4; ++j) {
      const float y = acc[i][j] * inv + bias;
      const float s = (y >= SPIKE_THRESH) ? 1.0f : 0.0f;
      float4 sv = make_float4(s, s, s, s);
      reinterpret_cast<float4*>(dst)[j * 2 + 0] = sv;
      reinterpret_cast<float4*>(dst)[j * 2 + 1] = sv;
    }
  }
}

extern "C" void kernel_launch(void* const* d_in, const int* in_sizes, int n_in,
                              void* d_out, int out_size, void* d_ws, size_t ws_size,
                              hipStream_t stream) {
  (void)in_sizes; (void)n_in; (void)out_size; (void)ws_size;
  const float* x      = (const float*)d_in[0];
  const float* w_qkv  = (const float*)d_in[1];
  const float* w_out  = (const float*)d_in[2];
  const float* gamma  = (const float*)d_in[3];
  const float* beta   = (const float*)d_in[4];
  const float* mean   = (const float*)d_in[5];
  const float* var    = (const float*)d_in[6];
  float* outp = (float*)d_out;

  // Scratch: xp (32MB) and qkv (96MB) live in the front of d_out (overwritten
  // by the final kernel only after they are consumed). att (32MB) in d_ws.
  float* xp  = outp;                                // (32,512,512)
  float* qkv = outp + (size_t)32 * 512 * 512;       // (32,1536,512)
  float* att = (float*)d_ws;                        // (32,512,512)

  pool_kernel<<<2048, 256, 0, stream>>>(x, xp, 32 * 512 * 512);

  dim3 gB(8, 24, 32);
  qkv_gemm_spike<<<gB, 256, 0, stream>>>(w_qkv, xp, qkv);

  attn_kernel<<<256, 256, 0, stream>>>(qkv, att);

  dim3 gD(8, 8, 32);
  out_gemm_bn_spike<<<gD, 256, 0, stream>>>(w_out, att, gamma, beta, mean, var, outp);
}

// Round 2
// 286.744 us; speedup vs baseline: 2.1678x; 2.1678x over previous
//
#include <hip/hip_runtime.h>
#include <math.h>

// SpikingSelfAttention on MI355X.
// pool8+transpose -> QKV MFMA-GEMM+spike -> attn (M=V*K^T trick, fp32, emits
// att^T) -> out MFMA-GEMM + BN + spike + repeat8.
// bf16 MFMA with exact-fp32 margin fallback (|preact-2|<margin -> recompute),
// so spike decisions match the fp32 reference.

#define THRESH 2.0f
#define BN_EPS 1e-5f

typedef __attribute__((ext_vector_type(4))) float f32x4;
typedef __attribute__((ext_vector_type(8))) short bfrag;   // 8 bf16 (4 VGPR)
typedef __attribute__((ext_vector_type(4))) short s16x4;   // 4 bf16 (8B)

__device__ __forceinline__ short f2bf(float f) {  // RNE f32->bf16
  union { float f; unsigned u; } v; v.f = f;
  unsigned r = (v.u + 0x7FFFu + ((v.u >> 16) & 1u)) >> 16;
  return (short)r;
}
__device__ __forceinline__ void gload16(const void* g, void* l) {
  __builtin_amdgcn_global_load_lds(
      (const __attribute__((address_space(1))) void*)g,
      (__attribute__((address_space(3))) void*)l, 16, 0, 0);
}

// ---------------- W_qkv f32 -> bf16 ----------------
__global__ __launch_bounds__(256) void wconv_kernel(const float* __restrict__ w,
                                                    short* __restrict__ wb, int n4) {
  int i = blockIdx.x * 256 + threadIdx.x;
  if (i < n4) {
    f32x4 v = ((const f32x4*)w)[i];
    s16x4 h;
    h.x = f2bf(v.x); h.y = f2bf(v.y); h.z = f2bf(v.z); h.w = f2bf(v.w);
    ((s16x4*)wb)[i] = h;
  }
}

// ---------------- pool8 + transpose: x(32,512,4096)f32 -> xpT(32,512t,512c)bf16
__global__ __launch_bounds__(256) void pool_t_kernel(const float* __restrict__ x,
                                                     short* __restrict__ xpT) {
  const int b = blockIdx.z, c0 = blockIdx.y * 64, t0 = blockIdx.x * 64;
  __shared__ float Ts[64][65];
  const int tid = threadIdx.x;
  const int tl = tid & 63, cb = tid >> 6;
  const float* xb = x + (size_t)b * 512 * 4096;
#pragma unroll
  for (int i = 0; i < 16; ++i) {
    int cl = cb * 16 + i;
    const float* p = xb + (size_t)(c0 + cl) * 4096 + (size_t)(t0 + tl) * 8;
    float4 a = *(const float4*)p, d = *(const float4*)(p + 4);
    Ts[tl][cl] = (((a.x + a.y) + (a.z + a.w)) + ((d.x + d.y) + (d.z + d.w))) * 0.125f;
  }
  __syncthreads();
  const int row = tid >> 2, cs = (tid & 3) * 16;
  short* dst = xpT + ((size_t)b * 512 + t0 + row) * 512 + c0 + cs;
#pragma unroll
  for (int k = 0; k < 4; ++k) {
    s16x4 h;
    h.x = f2bf(Ts[row][cs + 4 * k + 0]);
    h.y = f2bf(Ts[row][cs + 4 * k + 1]);
    h.z = f2bf(Ts[row][cs + 4 * k + 2]);
    h.w = f2bf(Ts[row][cs + 4 * k + 3]);
    ((s16x4*)dst)[k] = h;
  }
}

// ---------------- QKV GEMM (bf16 MFMA) + spike ----------------
// C[o,t] = sum_c W[o,c]*xpT[t,c]; 128x128 tile, BK=64, 4 waves.
__global__ __launch_bounds__(256) void qkv_gemm_mfma(
    const short* __restrict__ Wb, const short* __restrict__ XTb,
    const float* __restrict__ Wf, const float* __restrict__ x,
    float* __restrict__ qkv) {
  const int b = blockIdx.z, o0 = blockIdx.y * 128, t0 = blockIdx.x * 128;
  __shared__ __align__(16) short Asm[128 * 64];
  __shared__ __align__(16) short Bsm[128 * 64];
  const int tid = threadIdx.x, lane = tid & 63, wave = tid >> 6;
  const int wr = (wave >> 1) * 64, wc = (wave & 1) * 64;
  const int lrow = lane & 15, lk = (lane >> 4) * 8;
  f32x4 acc[4][4] = {};
  const short* Ag = Wb + (size_t)o0 * 512;
  const short* Bg = XTb + ((size_t)b * 512 + (size_t)t0) * 512;

  for (int k0 = 0; k0 < 512; k0 += 64) {
    __syncthreads();
#pragma unroll
    for (int i = 0; i < 4; ++i) {
      int idx = tid + 256 * i, row = idx >> 3, seg = idx & 7;
      gload16(Ag + (size_t)row * 512 + k0 + seg * 8, Asm + idx * 8);
    }
#pragma unroll
    for (int i = 0; i < 4; ++i) {
      int idx = tid + 256 * i, row = idx >> 3, seg = idx & 7;
      gload16(Bg + (size_t)row * 512 + k0 + seg * 8, Bsm + idx * 8);
    }
    __syncthreads();
#pragma unroll
    for (int kk = 0; kk < 64; kk += 32) {
      bfrag af[4], bfr[4];
#pragma unroll
      for (int mi = 0; mi < 4; ++mi)
        af[mi] = *(const bfrag*)(Asm + (wr + mi * 16 + lrow) * 64 + kk + lk);
#pragma unroll
      for (int ni = 0; ni < 4; ++ni)
        bfr[ni] = *(const bfrag*)(Bsm + (wc + ni * 16 + lrow) * 64 + kk + lk);
#pragma unroll
      for (int mi = 0; mi < 4; ++mi)
#pragma unroll
        for (int ni = 0; ni < 4; ++ni)
          acc[mi][ni] = __builtin_amdgcn_mfma_f32_16x16x32_bf16(
              af[mi], bfr[ni], acc[mi][ni], 0, 0, 0);
    }
  }

  float* Out = qkv + ((size_t)b * 1536 + o0) * 512 + t0;
  const int lrg = (lane >> 4) * 4;
  unsigned long long fb = 0;
#pragma unroll
  for (int mi = 0; mi < 4; ++mi)
#pragma unroll
    for (int ni = 0; ni < 4; ++ni)
#pragma unroll
      for (int r = 0; r < 4; ++r) {
        int rowl = wr + mi * 16 + lrg + r;
        int coll = wc + ni * 16 + lrow;
        float v = acc[mi][ni][r];
        if (fabsf(v - THRESH) < 0.05f) fb |= 1ull << (mi * 16 + ni * 4 + r);
        Out[(size_t)rowl * 512 + coll] = (v >= THRESH) ? 1.0f : 0.0f;
      }
  if (__builtin_expect(fb != 0, 0)) {  // exact fp32 recompute, ~never taken
    for (int bit = 0; bit < 64; ++bit) {
      if (!((fb >> bit) & 1)) continue;
      int mi = bit >> 4, ni = (bit >> 2) & 3, r = bit & 3;
      int rowl = wr + mi * 16 + lrg + r;
      int coll = wc + ni * 16 + lrow;
      const float* wrow = Wf + (size_t)(o0 + rowl) * 512;
      const float* xcol = x + (size_t)b * 512 * 4096 + (size_t)(t0 + coll) * 8;
      float s = 0.f;
      for (int c = 0; c < 512; ++c) {
        const float* xc = xcol + (size_t)c * 4096;
        float p = ((xc[0] + xc[1]) + (xc[2] + xc[3])) +
                  ((xc[4] + xc[5]) + (xc[6] + xc[7]));
        s += wrow[c] * (p * 0.125f);
      }
      Out[(size_t)rowl * 512 + coll] = (s >= THRESH) ? 1.0f : 0.0f;
    }
  }
}

// ---------------- attention: M = V K^T, O = scale*M Q, emits att^T ----------
__global__ __launch_bounds__(256) void attn_kernel(const float* __restrict__ qkv,
                                                   float* __restrict__ attT) {
  const int b = blockIdx.x >> 3;
  const int h = blockIdx.x & 7;
  const float* Q = qkv + (size_t)b * 1536 * 512 + (size_t)(h * 64) * 512;
  const float* K = qkv + (size_t)b * 1536 * 512 + (size_t)(512 + h * 64) * 512;
  const float* V = qkv + (size_t)b * 1536 * 512 + (size_t)(1024 + h * 64) * 512;

  __shared__ float Vs[16][64];
  __shared__ float Ks[16][64];
  __shared__ float Ms[64][64];
  __shared__ float Qs[64][64];
  __shared__ float Ts[64][65];

  const int tid = threadIdx.x;
  const int tx = tid & 15, ty = tid >> 4;
  const int l_r = tid >> 2, l_c = (tid & 3) << 2;

  // Phase 1: M[d,e] = sum_s V[d,s] * K[e,s]
  float m[4][4] = {};
  for (int s0 = 0; s0 < 512; s0 += 16) {
    float4 vv = *reinterpret_cast<const float4*>(V + (size_t)l_r * 512 + s0 + l_c);
    float4 kv = *reinterpret_cast<const float4*>(K + (size_t)l_r * 512 + s0 + l_c);
    __syncthreads();
    Vs[l_c + 0][l_r] = vv.x; Vs[l_c + 1][l_r] = vv.y;
    Vs[l_c + 2][l_r] = vv.z; Vs[l_c + 3][l_r] = vv.w;
    Ks[l_c + 0][l_r] = kv.x; Ks[l_c + 1][l_r] = kv.y;
    Ks[l_c + 2][l_r] = kv.z; Ks[l_c + 3][l_r] = kv.w;
    __syncthreads();
#pragma unroll
    for (int ss = 0; ss < 16; ++ss) {
      float4 vd = *reinterpret_cast<const float4*>(&Vs[ss][ty << 2]);
      float4 ke = *reinterpret_cast<const float4*>(&Ks[ss][tx << 2]);
      float vr[4] = {vd.x, vd.y, vd.z, vd.w};
      float kr[4] = {ke.x, ke.y, ke.z, ke.w};
#pragma unroll
      for (int i = 0; i < 4; ++i)
#pragma unroll
        for (int j = 0; j < 4; ++j) m[i][j] += vr[i] * kr[j];
    }
  }
  __syncthreads();
#pragma unroll
  for (int i = 0; i < 4; ++i)
#pragma unroll
    for (int j = 0; j < 4; ++j) Ms[(tx << 2) + j][(ty << 2) + i] = m[i][j];
  __syncthreads();

  // Phase 2: O[d,t] = 0.125 * sum_e Ms[e][d]*Q[e][t]; write attT[t][h*64+d]
  for (int tt = 0; tt < 512; tt += 64) {
#pragma unroll
    for (int r = 0; r < 4; ++r) {
      const int e = (tid >> 4) + r * 16;
      const int c = (tid & 15) << 2;
      *reinterpret_cast<float4*>(&Qs[e][c]) =
          *reinterpret_cast<const float4*>(Q + (size_t)e * 512 + tt + c);
    }
    __syncthreads();
    float acc[4][4] = {};
#pragma unroll
    for (int e = 0; e < 64; ++e) {
      float4 md = *reinterpret_cast<const float4*>(&Ms[e][ty << 2]);
      float4 qt = *reinterpret_cast<const float4*>(&Qs[e][tx << 2]);
      float mr[4] = {md.x, md.y, md.z, md.w};
      float qr[4] = {qt.x, qt.y, qt.z, qt.w};
#pragma unroll
      for (int i = 0; i < 4; ++i)
#pragma unroll
        for (int j = 0; j < 4; ++j) acc[i][j] += mr[i] * qr[j];
    }
#pragma unroll
    for (int i = 0; i < 4; ++i)
#pragma unroll
      for (int j = 0; j < 4; ++j)
        Ts[(tx << 2) + j][(ty << 2) + i] = acc[i][j] * 0.125f;
    __syncthreads();
    {
      const int row = tid >> 2, cseg = (tid & 3) * 16;
      float* dst = attT + ((size_t)b * 512 + tt + row) * 512 + h * 64 + cseg;
#pragma unroll
      for (int k = 0; k < 4; ++k)
        *reinterpret_cast<float4*>(dst + 4 * k) =
            *reinterpret_cast<const float4*>(&Ts[row][cseg + 4 * k]);
    }
  }
}

// ---------------- out GEMM (bf16 MFMA, reg-staged cvt) + BN + spike + rep8 --
__global__ __launch_bounds__(256) void out_gemm_mfma(
    const float* __restrict__ Wf, const float* __restrict__ attT,
    const float* __restrict__ gamma, const float* __restrict__ beta,
    const float* __restrict__ mean, const float* __restrict__ var,
    float* __restrict__ out) {
  const int b = blockIdx.z, o0 = blockIdx.y * 128, t0 = blockIdx.x * 128;
  __shared__ __align__(16) short Asm[128 * 64];
  __shared__ __align__(16) short Bsm[128 * 64];
  const int tid = threadIdx.x, lane = tid & 63, wave = tid >> 6;
  const int wr = (wave >> 1) * 64, wc = (wave & 1) * 64;
  const int lrow = lane & 15, lk = (lane >> 4) * 8;
  f32x4 acc[4][4] = {};
  const float* Bg = attT + ((size_t)b * 512 + t0) * 512;

  for (int k0 = 0; k0 < 512; k0 += 64) {
    f32x4 av[8], bv[8];
#pragma unroll
    for (int i = 0; i < 8; ++i) {
      int idx = tid + 256 * i, row = idx >> 4, cs = (idx & 15) * 4;
      av[i] = *(const f32x4*)(Wf + (size_t)(o0 + row) * 512 + k0 + cs);
      bv[i] = *(const f32x4*)(Bg + (size_t)row * 512 + k0 + cs);
    }
    __syncthreads();
#pragma unroll
    for (int i = 0; i < 8; ++i) {
      int idx = tid + 256 * i;
      s16x4 ha, hb;
      ha.x = f2bf(av[i].x); ha.y = f2bf(av[i].y);
      ha.z = f2bf(av[i].z); ha.w = f2bf(av[i].w);
      hb.x = f2bf(bv[i].x); hb.y = f2bf(bv[i].y);
      hb.z = f2bf(bv[i].z); hb.w = f2bf(bv[i].w);
      *(s16x4*)(Asm + idx * 4) = ha;
      *(s16x4*)(Bsm + idx * 4) = hb;
    }
    __syncthreads();
#pragma unroll
    for (int kk = 0; kk < 64; kk += 32) {
      bfrag af[4], bfr[4];
#pragma unroll
      for (int mi = 0; mi < 4; ++mi)
        af[mi] = *(const bfrag*)(Asm + (wr + mi * 16 + lrow) * 64 + kk + lk);
#pragma unroll
      for (int ni = 0; ni < 4; ++ni)
        bfr[ni] = *(const bfrag*)(Bsm + (wc + ni * 16 + lrow) * 64 + kk + lk);
#pragma unroll
      for (int mi = 0; mi < 4; ++mi)
#pragma unroll
        for (int ni = 0; ni < 4; ++ni)
          acc[mi][ni] = __builtin_amdgcn_mfma_f32_16x16x32_bf16(
              af[mi], bfr[ni], acc[mi][ni], 0, 0, 0);
    }
  }

  const int lrg = (lane >> 4) * 4;
  unsigned long long fbm = 0;
#pragma unroll
  for (int mi = 0; mi < 4; ++mi)
#pragma unroll
    for (int ni = 0; ni < 4; ++ni)
#pragma unroll
      for (int r = 0; r < 4; ++r) {
        int o = o0 + wr + mi * 16 + lrg + r;
        int tt = t0 + wc + ni * 16 + lrow;
        float inv = gamma[o] / sqrtf(var[o] + BN_EPS);
        float bias = beta[o] - mean[o] * inv;
        float y = acc[mi][ni][r] * inv + bias;
        if (fabsf(y - THRESH) < 0.02f) fbm |= 1ull << (mi * 16 + ni * 4 + r);
        float s = (y >= THRESH) ? 1.0f : 0.0f;
        float4 sv = make_float4(s, s, s, s);
        float* dp = out + ((size_t)b * 512 + o) * 4096 + (size_t)tt * 8;
        ((float4*)dp)[0] = sv;
        ((float4*)dp)[1] = sv;
      }
  if (__builtin_expect(fbm != 0, 0)) {  // exact fp32 recompute, ~never taken
    for (int bit = 0; bit < 64; ++bit) {
      if (!((fbm >> bit) & 1)) continue;
      int mi = bit >> 4, ni = (bit >> 2) & 3, r = bit & 3;
      int o = o0 + wr + mi * 16 + lrg + r;
      int tt = t0 + wc + ni * 16 + lrow;
      const float* wrow = Wf + (size_t)o * 512;
      const float* arow = attT + ((size_t)b * 512 + tt) * 512;
      float s = 0.f;
      for (int c = 0; c < 512; ++c) s += wrow[c] * arow[c];
      float inv = gamma[o] / sqrtf(var[o] + BN_EPS);
      float y = s * inv + (beta[o] - mean[o] * inv);
      float sp = (y >= THRESH) ? 1.0f : 0.0f;
      float4 sv = make_float4(sp, sp, sp, sp);
      float* dp = out + ((size_t)b * 512 + o) * 4096 + (size_t)tt * 8;
      ((float4*)dp)[0] = sv;
      ((float4*)dp)[1] = sv;
    }
  }
}

extern "C" void kernel_launch(void* const* d_in, const int* in_sizes, int n_in,
                              void* d_out, int out_size, void* d_ws, size_t ws_size,
                              hipStream_t stream) {
  (void)in_sizes; (void)n_in; (void)out_size; (void)ws_size;
  const float* x     = (const float*)d_in[0];
  const float* w_qkv = (const float*)d_in[1];
  const float* w_out = (const float*)d_in[2];
  const float* gamma = (const float*)d_in[3];
  const float* beta  = (const float*)d_in[4];
  const float* mean  = (const float*)d_in[5];
  const float* var   = (const float*)d_in[6];
  float* outp = (float*)d_out;

  // d_out-front scratch (all consumed before out_gemm_mfma writes d_out):
  //   [0,16MB)    xpT bf16 (32,512t,512c)
  //   [16,112MB)  qkv f32  (32,1536,512)
  //   [112MB,..)  W_qkv bf16 (1536,512)
  char* ob = (char*)d_out;
  short* xpT  = (short*)(ob);
  float* qkvb = (float*)(ob + ((size_t)16 << 20));
  short* Wqb  = (short*)(ob + ((size_t)112 << 20));
  float* attT = (float*)d_ws;  // f32 (32,512t,512c) = 32MB

  wconv_kernel<<<768, 256, 0, stream>>>(w_qkv, Wqb, 1536 * 512 / 4);
  pool_t_kernel<<<dim3(8, 8, 32), 256, 0, stream>>>(x, xpT);
  qkv_gemm_mfma<<<dim3(4, 12, 32), 256, 0, stream>>>(Wqb, xpT, w_qkv, x, qkvb);
  attn_kernel<<<256, 256, 0, stream>>>(qkvb, attT);
  out_gemm_mfma<<<dim3(4, 4, 32), 256, 0, stream>>>(w_out, attT, gamma, beta,
                                                    mean, var, outp);
}

// Round 3
// 260.407 us; speedup vs baseline: 2.3870x; 1.1011x over previous
//
#include <hip/hip_runtime.h>
#include <math.h>

// SpikingSelfAttention on MI355X.
// pool8+transpose -> QKV MFMA-GEMM+spike(bf16 out) -> attn (binary bf16 MFMA
// M=V*K^T, exact; fp32 phase 2) -> out MFMA-GEMM + BN + spike + repeat8.
// Spike decisions guarded by exact-fp32 margin fallback where bf16 rounding
// could matter (qkv GEMM, out GEMM). Attention itself is bit-exact.

#define THRESH 2.0f
#define BN_EPS 1e-5f

typedef __attribute__((ext_vector_type(4))) float f32x4;
typedef __attribute__((ext_vector_type(8))) short bfrag;   // 8 bf16
typedef __attribute__((ext_vector_type(4))) short s16x4;   // 4 bf16

__device__ __forceinline__ short f2bf(float f) {  // RNE f32->bf16
  union { float f; unsigned u; } v; v.f = f;
  unsigned r = (v.u + 0x7FFFu + ((v.u >> 16) & 1u)) >> 16;
  return (short)r;
}
__device__ __forceinline__ float bf2f(short s) {
  union { unsigned u; float f; } v;
  v.u = ((unsigned)(unsigned short)s) << 16;
  return v.f;
}
__device__ __forceinline__ void gload16(const void* g, void* l) {
  __builtin_amdgcn_global_load_lds(
      (const __attribute__((address_space(1))) void*)g,
      (__attribute__((address_space(3))) void*)l, 16, 0, 0);
}

// ---------------- weights f32 -> bf16 (both W_qkv and W_out) ----------------
__global__ __launch_bounds__(256) void wconv_kernel(const float* __restrict__ wq,
                                                    const float* __restrict__ wo,
                                                    short* __restrict__ wqb,
                                                    short* __restrict__ wob) {
  int i = blockIdx.x * 256 + threadIdx.x;  // quads; n1=196608, n2=65536
  const int n1 = 1536 * 512 / 4;
  f32x4 v;
  s16x4 h;
  if (i < n1) {
    v = ((const f32x4*)wq)[i];
    h.x = f2bf(v.x); h.y = f2bf(v.y); h.z = f2bf(v.z); h.w = f2bf(v.w);
    ((s16x4*)wqb)[i] = h;
  } else {
    int j = i - n1;
    v = ((const f32x4*)wo)[j];
    h.x = f2bf(v.x); h.y = f2bf(v.y); h.z = f2bf(v.z); h.w = f2bf(v.w);
    ((s16x4*)wob)[j] = h;
  }
}

// ---------------- pool8 + transpose: x(32,512,4096)f32 -> xpT(32,512t,512c)bf16
__global__ __launch_bounds__(256) void pool_t_kernel(const float* __restrict__ x,
                                                     short* __restrict__ xpT) {
  const int b = blockIdx.z, c0 = blockIdx.y * 64, t0 = blockIdx.x * 64;
  __shared__ float Ts[64][65];
  const int tid = threadIdx.x;
  const int tl = tid & 63, cb = tid >> 6;
  const float* xb = x + (size_t)b * 512 * 4096;
#pragma unroll
  for (int i = 0; i < 16; ++i) {
    int cl = cb * 16 + i;
    const float* p = xb + (size_t)(c0 + cl) * 4096 + (size_t)(t0 + tl) * 8;
    float4 a = *(const float4*)p, d = *(const float4*)(p + 4);
    Ts[tl][cl] = (((a.x + a.y) + (a.z + a.w)) + ((d.x + d.y) + (d.z + d.w))) * 0.125f;
  }
  __syncthreads();
  const int row = tid >> 2, cs = (tid & 3) * 16;
  short* dst = xpT + ((size_t)b * 512 + t0 + row) * 512 + c0 + cs;
#pragma unroll
  for (int k = 0; k < 4; ++k) {
    s16x4 h;
    h.x = f2bf(Ts[row][cs + 4 * k + 0]);
    h.y = f2bf(Ts[row][cs + 4 * k + 1]);
    h.z = f2bf(Ts[row][cs + 4 * k + 2]);
    h.w = f2bf(Ts[row][cs + 4 * k + 3]);
    ((s16x4*)dst)[k] = h;
  }
}

// ---------------- QKV GEMM (bf16 MFMA) + spike -> bf16 spikes ----------------
__global__ __launch_bounds__(256) void qkv_gemm_mfma(
    const short* __restrict__ Wb, const short* __restrict__ XTb,
    const float* __restrict__ Wf, const float* __restrict__ x,
    short* __restrict__ qkv) {
  const int b = blockIdx.z, o0 = blockIdx.y * 128, t0 = blockIdx.x * 128;
  __shared__ __align__(16) short Asm[128 * 64];
  __shared__ __align__(16) short Bsm[128 * 64];
  const int tid = threadIdx.x, lane = tid & 63, wave = tid >> 6;
  const int wr = (wave >> 1) * 64, wc = (wave & 1) * 64;
  const int lrow = lane & 15, lk = (lane >> 4) * 8;
  f32x4 acc[4][4] = {};
  const short* Ag = Wb + (size_t)o0 * 512;
  const short* Bg = XTb + ((size_t)b * 512 + (size_t)t0) * 512;

  for (int k0 = 0; k0 < 512; k0 += 64) {
    __syncthreads();
#pragma unroll
    for (int i = 0; i < 4; ++i) {
      int idx = tid + 256 * i, row = idx >> 3, seg = idx & 7;
      gload16(Ag + (size_t)row * 512 + k0 + seg * 8, Asm + idx * 8);
    }
#pragma unroll
    for (int i = 0; i < 4; ++i) {
      int idx = tid + 256 * i, row = idx >> 3, seg = idx & 7;
      gload16(Bg + (size_t)row * 512 + k0 + seg * 8, Bsm + idx * 8);
    }
    __syncthreads();
#pragma unroll
    for (int kk = 0; kk < 64; kk += 32) {
      bfrag af[4], bfr[4];
#pragma unroll
      for (int mi = 0; mi < 4; ++mi)
        af[mi] = *(const bfrag*)(Asm + (wr + mi * 16 + lrow) * 64 + kk + lk);
#pragma unroll
      for (int ni = 0; ni < 4; ++ni)
        bfr[ni] = *(const bfrag*)(Bsm + (wc + ni * 16 + lrow) * 64 + kk + lk);
#pragma unroll
      for (int mi = 0; mi < 4; ++mi)
#pragma unroll
        for (int ni = 0; ni < 4; ++ni)
          acc[mi][ni] = __builtin_amdgcn_mfma_f32_16x16x32_bf16(
              af[mi], bfr[ni], acc[mi][ni], 0, 0, 0);
    }
  }

  short* Out = qkv + ((size_t)b * 1536 + o0) * 512 + t0;
  const int lrg = (lane >> 4) * 4;
  unsigned long long fb = 0;
#pragma unroll
  for (int mi = 0; mi < 4; ++mi)
#pragma unroll
    for (int ni = 0; ni < 4; ++ni)
#pragma unroll
      for (int r = 0; r < 4; ++r) {
        int rowl = wr + mi * 16 + lrg + r;
        int coll = wc + ni * 16 + lrow;
        float v = acc[mi][ni][r];
        if (fabsf(v - THRESH) < 0.05f) fb |= 1ull << (mi * 16 + ni * 4 + r);
        Out[(size_t)rowl * 512 + coll] = (v >= THRESH) ? (short)0x3F80 : (short)0;
      }
  if (__builtin_expect(fb != 0, 0)) {  // exact fp32 recompute, ~never taken
    for (int bit = 0; bit < 64; ++bit) {
      if (!((fb >> bit) & 1)) continue;
      int mi = bit >> 4, ni = (bit >> 2) & 3, r = bit & 3;
      int rowl = wr + mi * 16 + lrg + r;
      int coll = wc + ni * 16 + lrow;
      const float* wrow = Wf + (size_t)(o0 + rowl) * 512;
      const float* xcol = x + (size_t)b * 512 * 4096 + (size_t)(t0 + coll) * 8;
      float s = 0.f;
      for (int c = 0; c < 512; ++c) {
        const float* xc = xcol + (size_t)c * 4096;
        float p = ((xc[0] + xc[1]) + (xc[2] + xc[3])) +
                  ((xc[4] + xc[5]) + (xc[6] + xc[7]));
        s += wrow[c] * (p * 0.125f);
      }
      Out[(size_t)rowl * 512 + coll] = (s >= THRESH) ? (short)0x3F80 : (short)0;
    }
  }
}

// ---------------- attention: M = V K^T (bf16 MFMA, exact on binary spikes),
// O = scale * M Q (fp32 vector); emits attT f32 and attTb bf16.
__global__ __launch_bounds__(256) void attn_kernel(const short* __restrict__ qkvb,
                                                   float* __restrict__ attT,
                                                   short* __restrict__ attTb) {
  const int b = blockIdx.z, h = blockIdx.y, th = blockIdx.x;  // th: t-half
  const short* Q = qkvb + ((size_t)b * 1536 + h * 64) * 512;
  const short* K = qkvb + ((size_t)b * 1536 + 512 + h * 64) * 512;
  const short* V = qkvb + ((size_t)b * 1536 + 1024 + h * 64) * 512;

  __shared__ float Ms[64][65];  // Ms[e][d]
  __shared__ float Qs[64][65];  // Qs[e][tloc]
  __shared__ float Ts[64][65];  // Ts[tloc][d]

  const int tid = threadIdx.x, lane = tid & 63, wave = tid >> 6;
  const int lrow = lane & 15, lk = (lane >> 4) * 8, lrg = (lane >> 4) * 4;

  // Phase 1: wave w computes M[d=16w..16w+15][all e], K-reduce over s=512.
  // Direct global loads (per-head K/V are 64KB, L2-resident). Exact: binary.
  f32x4 mAcc[4] = {};
#pragma unroll 4
  for (int kk = 0; kk < 512; kk += 32) {
    bfrag a = *(const bfrag*)(V + (size_t)(wave * 16 + lrow) * 512 + kk + lk);
#pragma unroll
    for (int ni = 0; ni < 4; ++ni) {
      bfrag bb = *(const bfrag*)(K + (size_t)(ni * 16 + lrow) * 512 + kk + lk);
      mAcc[ni] = __builtin_amdgcn_mfma_f32_16x16x32_bf16(a, bb, mAcc[ni], 0, 0, 0);
    }
  }
#pragma unroll
  for (int ni = 0; ni < 4; ++ni)
#pragma unroll
    for (int r = 0; r < 4; ++r)
      Ms[ni * 16 + lrow][wave * 16 + lrg + r] = mAcc[ni][r];
  __syncthreads();

  // Phase 2: O[d][t] = 0.125 * sum_e Ms[e][d] * Q[e][t], for this t-half.
  const int tx = tid & 15, ty = tid >> 4;
  const int srow = tid >> 2, scseg = (tid & 3) * 16;
  for (int tt = th * 256; tt < th * 256 + 256; tt += 64) {
    {  // stage Qs[e][0..63] f32 from bf16
      bfrag q0 = *(const bfrag*)(Q + (size_t)srow * 512 + tt + scseg);
      bfrag q1 = *(const bfrag*)(Q + (size_t)srow * 512 + tt + scseg + 8);
#pragma unroll
      for (int j = 0; j < 8; ++j) {
        Qs[srow][scseg + j] = bf2f(q0[j]);
        Qs[srow][scseg + 8 + j] = bf2f(q1[j]);
      }
    }
    __syncthreads();
    float acc[4][4] = {};
#pragma unroll
    for (int e = 0; e < 64; ++e) {
      float4 md = *reinterpret_cast<const float4*>(&Ms[e][ty << 2]);
      float4 qt = *reinterpret_cast<const float4*>(&Qs[e][tx << 2]);
      float mr[4] = {md.x, md.y, md.z, md.w};
      float qr[4] = {qt.x, qt.y, qt.z, qt.w};
#pragma unroll
      for (int i = 0; i < 4; ++i)
#pragma unroll
        for (int j = 0; j < 4; ++j) acc[i][j] += mr[i] * qr[j];
    }
#pragma unroll
    for (int i = 0; i < 4; ++i)
#pragma unroll
      for (int j = 0; j < 4; ++j)
        Ts[(tx << 2) + j][(ty << 2) + i] = acc[i][j] * 0.125f;
    __syncthreads();
    {  // write attT (f32, exact) and attTb (bf16 for MFMA)
      float* dst = attT + ((size_t)b * 512 + tt + srow) * 512 + h * 64 + scseg;
      short* dstb = attTb + ((size_t)b * 512 + tt + srow) * 512 + h * 64 + scseg;
#pragma unroll
      for (int k = 0; k < 4; ++k) {
        float4 v = *reinterpret_cast<const float4*>(&Ts[srow][scseg + 4 * k]);
        *reinterpret_cast<float4*>(dst + 4 * k) = v;
        s16x4 hh;
        hh.x = f2bf(v.x); hh.y = f2bf(v.y); hh.z = f2bf(v.z); hh.w = f2bf(v.w);
        ((s16x4*)dstb)[k] = hh;
      }
    }
    __syncthreads();
  }
}

// ---------------- out GEMM (bf16 MFMA, gload16) + BN + spike + repeat8 ------
__global__ __launch_bounds__(256) void out_gemm_mfma(
    const short* __restrict__ Wob, const short* __restrict__ attTb,
    const float* __restrict__ Wf, const float* __restrict__ attT,
    const float* __restrict__ gamma, const float* __restrict__ beta,
    const float* __restrict__ mean, const float* __restrict__ var,
    float* __restrict__ out) {
  const int b = blockIdx.z, o0 = blockIdx.y * 128, t0 = blockIdx.x * 128;
  __shared__ __align__(16) short Asm[128 * 64];
  __shared__ __align__(16) short Bsm[128 * 64];
  const int tid = threadIdx.x, lane = tid & 63, wave = tid >> 6;
  const int wr = (wave >> 1) * 64, wc = (wave & 1) * 64;
  const int lrow = lane & 15, lk = (lane >> 4) * 8;
  f32x4 acc[4][4] = {};
  const short* Ag = Wob + (size_t)o0 * 512;
  const short* Bg = attTb + ((size_t)b * 512 + t0) * 512;

  for (int k0 = 0; k0 < 512; k0 += 64) {
    __syncthreads();
#pragma unroll
    for (int i = 0; i < 4; ++i) {
      int idx = tid + 256 * i, row = idx >> 3, seg = idx & 7;
      gload16(Ag + (size_t)row * 512 + k0 + seg * 8, Asm + idx * 8);
    }
#pragma unroll
    for (int i = 0; i < 4; ++i) {
      int idx = tid + 256 * i, row = idx >> 3, seg = idx & 7;
      gload16(Bg + (size_t)row * 512 + k0 + seg * 8, Bsm + idx * 8);
    }
    __syncthreads();
#pragma unroll
    for (int kk = 0; kk < 64; kk += 32) {
      bfrag af[4], bfr[4];
#pragma unroll
      for (int mi = 0; mi < 4; ++mi)
        af[mi] = *(const bfrag*)(Asm + (wr + mi * 16 + lrow) * 64 + kk + lk);
#pragma unroll
      for (int ni = 0; ni < 4; ++ni)
        bfr[ni] = *(const bfrag*)(Bsm + (wc + ni * 16 + lrow) * 64 + kk + lk);
#pragma unroll
      for (int mi = 0; mi < 4; ++mi)
#pragma unroll
        for (int ni = 0; ni < 4; ++ni)
          acc[mi][ni] = __builtin_amdgcn_mfma_f32_16x16x32_bf16(
              af[mi], bfr[ni], acc[mi][ni], 0, 0, 0);
    }
  }

  const int lrg = (lane >> 4) * 4;
  unsigned long long fbm = 0;
#pragma unroll
  for (int mi = 0; mi < 4; ++mi)
#pragma unroll
    for (int r = 0; r < 4; ++r) {
      const int o = o0 + wr + mi * 16 + lrg + r;
      const float inv = gamma[o] / sqrtf(var[o] + BN_EPS);
      const float bias = beta[o] - mean[o] * inv;
#pragma unroll
      for (int ni = 0; ni < 4; ++ni) {
        int tt = t0 + wc + ni * 16 + lrow;
        float y = acc[mi][ni][r] * inv + bias;
        if (fabsf(y - THRESH) < 0.02f) fbm |= 1ull << (mi * 16 + ni * 4 + r);
        float s = (y >= THRESH) ? 1.0f : 0.0f;
        float4 sv = make_float4(s, s, s, s);
        float* dp = out + ((size_t)b * 512 + o) * 4096 + (size_t)tt * 8;
        ((float4*)dp)[0] = sv;
        ((float4*)dp)[1] = sv;
      }
    }
  if (__builtin_expect(fbm != 0, 0)) {  // exact fp32 recompute, ~never taken
    for (int bit = 0; bit < 64; ++bit) {
      if (!((fbm >> bit) & 1)) continue;
      int mi = bit >> 4, ni = (bit >> 2) & 3, r = bit & 3;
      int o = o0 + wr + mi * 16 + lrg + r;
      int tt = t0 + wc + ni * 16 + lrow;
      const float* wrow = Wf + (size_t)o * 512;
      const float* arow = attT + ((size_t)b * 512 + tt) * 512;
      float s = 0.f;
      for (int c = 0; c < 512; ++c) s += wrow[c] * arow[c];
      float inv = gamma[o] / sqrtf(var[o] + BN_EPS);
      float y = s * inv + (beta[o] - mean[o] * inv);
      float sp = (y >= THRESH) ? 1.0f : 0.0f;
      float4 sv = make_float4(sp, sp, sp, sp);
      float* dp = out + ((size_t)b * 512 + o) * 4096 + (size_t)tt * 8;
      ((float4*)dp)[0] = sv;
      ((float4*)dp)[1] = sv;
    }
  }
}

extern "C" void kernel_launch(void* const* d_in, const int* in_sizes, int n_in,
                              void* d_out, int out_size, void* d_ws, size_t ws_size,
                              hipStream_t stream) {
  (void)in_sizes; (void)n_in; (void)out_size; (void)ws_size;
  const float* x     = (const float*)d_in[0];
  const float* w_qkv = (const float*)d_in[1];
  const float* w_out = (const float*)d_in[2];
  const float* gamma = (const float*)d_in[3];
  const float* beta  = (const float*)d_in[4];
  const float* mean  = (const float*)d_in[5];
  const float* var   = (const float*)d_in[6];
  float* outp = (float*)d_out;

  // d_out-front scratch: consumed BEFORE out_gemm writes d_out.
  //   [0,16MB)   xpT  bf16 (32,512t,512c)
  //   [16,64MB)  qkvb bf16 (32,1536,512)
  // d_ws scratch (out_gemm inputs must NOT alias d_out):
  //   [0,32MB)   attT  f32  (32,512t,512c)
  //   [32,48MB)  attTb bf16 (32,512t,512c)
  //   [48,..)    Wqb bf16 (1536,512), Wob bf16 (512,512)
  char* ob = (char*)d_out;
  char* wb = (char*)d_ws;
  short* xpT  = (short*)(ob);
  short* qkvb = (short*)(ob + ((size_t)16 << 20));
  float* attT  = (float*)(wb);
  short* attTb = (short*)(wb + ((size_t)32 << 20));
  short* Wqb   = (short*)(wb + ((size_t)48 << 20));
  short* Wob   = (short*)(wb + ((size_t)50 << 20));

  wconv_kernel<<<1024, 256, 0, stream>>>(w_qkv, w_out, Wqb, Wob);
  pool_t_kernel<<<dim3(8, 8, 32), 256, 0, stream>>>(x, xpT);
  qkv_gemm_mfma<<<dim3(4, 12, 32), 256, 0, stream>>>(Wqb, xpT, w_qkv, x, qkvb);
  attn_kernel<<<dim3(2, 8, 32), 256, 0, stream>>>(qkvb, attT, attTb);
  out_gemm_mfma<<<dim3(4, 4, 32), 256, 0, stream>>>(Wob, attTb, w_out, attT,
                                                    gamma, beta, mean, var, outp);
}

// Round 4
// 217.846 us; speedup vs baseline: 2.8534x; 1.1954x over previous
//
#include <hip/hip_runtime.h>
#include <math.h>

// SpikingSelfAttention on MI355X — event-driven (spike-sparsity-aware).
// pool8+transpose -> QKV MFMA-GEMM+spike(bf16 out, per-batch spike flags) ->
// attn (skipped for spike-free batches) -> out GEMM (bias fast path for
// spike-free batches) + BN + spike + repeat8.
// Correct for arbitrary inputs: flags are computed from actual spike
// decisions; dense paths run whenever a batch has any spike.

#define THRESH 2.0f
#define BN_EPS 1e-5f

typedef __attribute__((ext_vector_type(4))) float f32x4;
typedef __attribute__((ext_vector_type(8))) short bfrag;   // 8 bf16
typedef __attribute__((ext_vector_type(4))) short s16x4;   // 4 bf16

__device__ __forceinline__ short f2bf(float f) {  // RNE f32->bf16
  union { float f; unsigned u; } v; v.f = f;
  unsigned r = (v.u + 0x7FFFu + ((v.u >> 16) & 1u)) >> 16;
  return (short)r;
}
__device__ __forceinline__ float bf2f(short s) {
  union { unsigned u; float f; } v;
  v.u = ((unsigned)(unsigned short)s) << 16;
  return v.f;
}
__device__ __forceinline__ void gload16(const void* g, void* l) {
  __builtin_amdgcn_global_load_lds(
      (const __attribute__((address_space(1))) void*)g,
      (__attribute__((address_space(3))) void*)l, 16, 0, 0);
}

// ------- weights f32 -> bf16 (W_qkv, W_out) + zero the spike flags ----------
__global__ __launch_bounds__(256) void wconv_kernel(const float* __restrict__ wq,
                                                    const float* __restrict__ wo,
                                                    short* __restrict__ wqb,
                                                    short* __restrict__ wob,
                                                    int* __restrict__ flags) {
  int i = blockIdx.x * 256 + threadIdx.x;  // quads; n1=196608, n2=65536
  const int n1 = 1536 * 512 / 4;
  if (i < 32) flags[i] = 0;
  f32x4 v;
  s16x4 h;
  if (i < n1) {
    v = ((const f32x4*)wq)[i];
    h.x = f2bf(v.x); h.y = f2bf(v.y); h.z = f2bf(v.z); h.w = f2bf(v.w);
    ((s16x4*)wqb)[i] = h;
  } else {
    int j = i - n1;
    v = ((const f32x4*)wo)[j];
    h.x = f2bf(v.x); h.y = f2bf(v.y); h.z = f2bf(v.z); h.w = f2bf(v.w);
    ((s16x4*)wob)[j] = h;
  }
}

// ---------------- pool8 + transpose: x(32,512,4096)f32 -> xpT(32,512t,512c)bf16
__global__ __launch_bounds__(256) void pool_t_kernel(const float* __restrict__ x,
                                                     short* __restrict__ xpT) {
  const int b = blockIdx.z, c0 = blockIdx.y * 64, t0 = blockIdx.x * 64;
  __shared__ float Ts[64][65];
  const int tid = threadIdx.x;
  const int tl = tid & 63, cb = tid >> 6;
  const float* xb = x + (size_t)b * 512 * 4096;
#pragma unroll
  for (int i = 0; i < 16; ++i) {
    int cl = cb * 16 + i;
    const float* p = xb + (size_t)(c0 + cl) * 4096 + (size_t)(t0 + tl) * 8;
    float4 a = *(const float4*)p, d = *(const float4*)(p + 4);
    Ts[tl][cl] = (((a.x + a.y) + (a.z + a.w)) + ((d.x + d.y) + (d.z + d.w))) * 0.125f;
  }
  __syncthreads();
  const int row = tid >> 2, cs = (tid & 3) * 16;
  short* dst = xpT + ((size_t)b * 512 + t0 + row) * 512 + c0 + cs;
#pragma unroll
  for (int k = 0; k < 4; ++k) {
    s16x4 h;
    h.x = f2bf(Ts[row][cs + 4 * k + 0]);
    h.y = f2bf(Ts[row][cs + 4 * k + 1]);
    h.z = f2bf(Ts[row][cs + 4 * k + 2]);
    h.w = f2bf(Ts[row][cs + 4 * k + 3]);
    ((s16x4*)dst)[k] = h;
  }
}

// ------- QKV GEMM (bf16 MFMA) + spike -> bf16 spikes + per-batch flag -------
__global__ __launch_bounds__(256) void qkv_gemm_mfma(
    const short* __restrict__ Wb, const short* __restrict__ XTb,
    const float* __restrict__ Wf, const float* __restrict__ x,
    short* __restrict__ qkv, int* __restrict__ flags) {
  const int b = blockIdx.z, o0 = blockIdx.y * 128, t0 = blockIdx.x * 128;
  __shared__ __align__(16) short Asm[128 * 64];
  __shared__ __align__(16) short Bsm[128 * 64];
  const int tid = threadIdx.x, lane = tid & 63, wave = tid >> 6;
  const int wr = (wave >> 1) * 64, wc = (wave & 1) * 64;
  const int lrow = lane & 15, lk = (lane >> 4) * 8;
  f32x4 acc[4][4] = {};
  const short* Ag = Wb + (size_t)o0 * 512;
  const short* Bg = XTb + ((size_t)b * 512 + (size_t)t0) * 512;

  for (int k0 = 0; k0 < 512; k0 += 64) {
    __syncthreads();
#pragma unroll
    for (int i = 0; i < 4; ++i) {
      int idx = tid + 256 * i, row = idx >> 3, seg = idx & 7;
      gload16(Ag + (size_t)row * 512 + k0 + seg * 8, Asm + idx * 8);
    }
#pragma unroll
    for (int i = 0; i < 4; ++i) {
      int idx = tid + 256 * i, row = idx >> 3, seg = idx & 7;
      gload16(Bg + (size_t)row * 512 + k0 + seg * 8, Bsm + idx * 8);
    }
    __syncthreads();
#pragma unroll
    for (int kk = 0; kk < 64; kk += 32) {
      bfrag af[4], bfr[4];
#pragma unroll
      for (int mi = 0; mi < 4; ++mi)
        af[mi] = *(const bfrag*)(Asm + (wr + mi * 16 + lrow) * 64 + kk + lk);
#pragma unroll
      for (int ni = 0; ni < 4; ++ni)
        bfr[ni] = *(const bfrag*)(Bsm + (wc + ni * 16 + lrow) * 64 + kk + lk);
#pragma unroll
      for (int mi = 0; mi < 4; ++mi)
#pragma unroll
        for (int ni = 0; ni < 4; ++ni)
          acc[mi][ni] = __builtin_amdgcn_mfma_f32_16x16x32_bf16(
              af[mi], bfr[ni], acc[mi][ni], 0, 0, 0);
    }
  }

  short* Out = qkv + ((size_t)b * 1536 + o0) * 512 + t0;
  const int lrg = (lane >> 4) * 4;
  unsigned long long fb = 0;
  bool anyspike = false;
#pragma unroll
  for (int mi = 0; mi < 4; ++mi)
#pragma unroll
    for (int ni = 0; ni < 4; ++ni)
#pragma unroll
      for (int r = 0; r < 4; ++r) {
        int rowl = wr + mi * 16 + lrg + r;
        int coll = wc + ni * 16 + lrow;
        float v = acc[mi][ni][r];
        if (fabsf(v - THRESH) < 0.05f) fb |= 1ull << (mi * 16 + ni * 4 + r);
        else anyspike |= (v >= THRESH);
        Out[(size_t)rowl * 512 + coll] = (v >= THRESH) ? (short)0x3F80 : (short)0;
      }
  if (__builtin_expect(fb != 0, 0)) {  // exact fp32 recompute, ~never taken
    for (int bit = 0; bit < 64; ++bit) {
      if (!((fb >> bit) & 1)) continue;
      int mi = bit >> 4, ni = (bit >> 2) & 3, r = bit & 3;
      int rowl = wr + mi * 16 + lrg + r;
      int coll = wc + ni * 16 + lrow;
      const float* wrow = Wf + (size_t)(o0 + rowl) * 512;
      const float* xcol = x + (size_t)b * 512 * 4096 + (size_t)(t0 + coll) * 8;
      float s = 0.f;
      for (int c = 0; c < 512; ++c) {
        const float* xc = xcol + (size_t)c * 4096;
        float p = ((xc[0] + xc[1]) + (xc[2] + xc[3])) +
                  ((xc[4] + xc[5]) + (xc[6] + xc[7]));
        s += wrow[c] * (p * 0.125f);
      }
      bool sp = (s >= THRESH);
      anyspike |= sp;
      Out[(size_t)rowl * 512 + coll] = sp ? (short)0x3F80 : (short)0;
    }
  }
  unsigned long long bal = __ballot(anyspike);
  if (lane == 0 && bal != 0ull) atomicOr(&flags[b], 1);
}

// ------- attention (only for batches with spikes): M = V K^T (bf16 MFMA,
// exact on binary spikes), O = scale * M Q (fp32); emits attT f32 + attTb bf16.
__global__ __launch_bounds__(256) void attn_kernel(const short* __restrict__ qkvb,
                                                   float* __restrict__ attT,
                                                   short* __restrict__ attTb,
                                                   const int* __restrict__ flags) {
  const int b = blockIdx.z, h = blockIdx.y, th = blockIdx.x;  // th: t-half
  if (flags[b] == 0) return;  // no spikes in this batch -> attn output is 0
  const short* Q = qkvb + ((size_t)b * 1536 + h * 64) * 512;
  const short* K = qkvb + ((size_t)b * 1536 + 512 + h * 64) * 512;
  const short* V = qkvb + ((size_t)b * 1536 + 1024 + h * 64) * 512;

  __shared__ float Ms[64][65];  // Ms[e][d]
  __shared__ float Qs[64][65];  // Qs[e][tloc]
  __shared__ float Ts[64][65];  // Ts[tloc][d]

  const int tid = threadIdx.x, lane = tid & 63, wave = tid >> 6;
  const int lrow = lane & 15, lk = (lane >> 4) * 8, lrg = (lane >> 4) * 4;

  f32x4 mAcc[4] = {};
#pragma unroll 4
  for (int kk = 0; kk < 512; kk += 32) {
    bfrag a = *(const bfrag*)(V + (size_t)(wave * 16 + lrow) * 512 + kk + lk);
#pragma unroll
    for (int ni = 0; ni < 4; ++ni) {
      bfrag bb = *(const bfrag*)(K + (size_t)(ni * 16 + lrow) * 512 + kk + lk);
      mAcc[ni] = __builtin_amdgcn_mfma_f32_16x16x32_bf16(a, bb, mAcc[ni], 0, 0, 0);
    }
  }
#pragma unroll
  for (int ni = 0; ni < 4; ++ni)
#pragma unroll
    for (int r = 0; r < 4; ++r)
      Ms[ni * 16 + lrow][wave * 16 + lrg + r] = mAcc[ni][r];
  __syncthreads();

  const int tx = tid & 15, ty = tid >> 4;
  const int srow = tid >> 2, scseg = (tid & 3) * 16;
  for (int tt = th * 256; tt < th * 256 + 256; tt += 64) {
    {
      bfrag q0 = *(const bfrag*)(Q + (size_t)srow * 512 + tt + scseg);
      bfrag q1 = *(const bfrag*)(Q + (size_t)srow * 512 + tt + scseg + 8);
#pragma unroll
      for (int j = 0; j < 8; ++j) {
        Qs[srow][scseg + j] = bf2f(q0[j]);
        Qs[srow][scseg + 8 + j] = bf2f(q1[j]);
      }
    }
    __syncthreads();
    float acc[4][4] = {};
#pragma unroll
    for (int e = 0; e < 64; ++e) {
      float4 md = *reinterpret_cast<const float4*>(&Ms[e][ty << 2]);
      float4 qt = *reinterpret_cast<const float4*>(&Qs[e][tx << 2]);
      float mr[4] = {md.x, md.y, md.z, md.w};
      float qr[4] = {qt.x, qt.y, qt.z, qt.w};
#pragma unroll
      for (int i = 0; i < 4; ++i)
#pragma unroll
        for (int j = 0; j < 4; ++j) acc[i][j] += mr[i] * qr[j];
    }
#pragma unroll
    for (int i = 0; i < 4; ++i)
#pragma unroll
      for (int j = 0; j < 4; ++j)
        Ts[(tx << 2) + j][(ty << 2) + i] = acc[i][j] * 0.125f;
    __syncthreads();
    {
      float* dst = attT + ((size_t)b * 512 + tt + srow) * 512 + h * 64 + scseg;
      short* dstb = attTb + ((size_t)b * 512 + tt + srow) * 512 + h * 64 + scseg;
#pragma unroll
      for (int k = 0; k < 4; ++k) {
        float4 v = *reinterpret_cast<const float4*>(&Ts[srow][scseg + 4 * k]);
        *reinterpret_cast<float4*>(dst + 4 * k) = v;
        s16x4 hh;
        hh.x = f2bf(v.x); hh.y = f2bf(v.y); hh.z = f2bf(v.z); hh.w = f2bf(v.w);
        ((s16x4*)dstb)[k] = hh;
      }
    }
    __syncthreads();
  }
}

// ------- out GEMM + BN + spike + repeat8; bias fast path when batch spike-free
__global__ __launch_bounds__(256) void out_gemm_mfma(
    const short* __restrict__ Wob, const short* __restrict__ attTb,
    const float* __restrict__ Wf, const float* __restrict__ attT,
    const float* __restrict__ gamma, const float* __restrict__ beta,
    const float* __restrict__ mean, const float* __restrict__ var,
    float* __restrict__ out, const int* __restrict__ flags) {
  const int b = blockIdx.z, o0 = blockIdx.y * 128, t0 = blockIdx.x * 128;
  const int tid = threadIdx.x;

  if (flags[b] == 0) {
    // attn output is exactly 0 -> y = beta - mean*inv, uniform over t.
    __shared__ float sRow[128];
    if (tid < 128) {
      int o = o0 + tid;
      float inv = gamma[o] / sqrtf(var[o] + BN_EPS);
      float y = beta[o] - mean[o] * inv;
      sRow[tid] = (y >= THRESH) ? 1.0f : 0.0f;
    }
    __syncthreads();
    float* base = out + ((size_t)b * 512 + o0) * 4096 + (size_t)t0 * 8;
    for (int r = 0; r < 128; ++r) {
      float s = sRow[r];
      float4 sv = make_float4(s, s, s, s);
      reinterpret_cast<float4*>(base + (size_t)r * 4096)[tid] = sv;
    }
    return;
  }

  __shared__ __align__(16) short Asm[128 * 64];
  __shared__ __align__(16) short Bsm[128 * 64];
  const int lane = tid & 63, wave = tid >> 6;
  const int wr = (wave >> 1) * 64, wc = (wave & 1) * 64;
  const int lrow = lane & 15, lk = (lane >> 4) * 8;
  f32x4 acc[4][4] = {};
  const short* Ag = Wob + (size_t)o0 * 512;
  const short* Bg = attTb + ((size_t)b * 512 + t0) * 512;

  for (int k0 = 0; k0 < 512; k0 += 64) {
    __syncthreads();
#pragma unroll
    for (int i = 0; i < 4; ++i) {
      int idx = tid + 256 * i, row = idx >> 3, seg = idx & 7;
      gload16(Ag + (size_t)row * 512 + k0 + seg * 8, Asm + idx * 8);
    }
#pragma unroll
    for (int i = 0; i < 4; ++i) {
      int idx = tid + 256 * i, row = idx >> 3, seg = idx & 7;
      gload16(Bg + (size_t)row * 512 + k0 + seg * 8, Bsm + idx * 8);
    }
    __syncthreads();
#pragma unroll
    for (int kk = 0; kk < 64; kk += 32) {
      bfrag af[4], bfr[4];
#pragma unroll
      for (int mi = 0; mi < 4; ++mi)
        af[mi] = *(const bfrag*)(Asm + (wr + mi * 16 + lrow) * 64 + kk + lk);
#pragma unroll
      for (int ni = 0; ni < 4; ++ni)
        bfr[ni] = *(const bfrag*)(Bsm + (wc + ni * 16 + lrow) * 64 + kk + lk);
#pragma unroll
      for (int mi = 0; mi < 4; ++mi)
#pragma unroll
        for (int ni = 0; ni < 4; ++ni)
          acc[mi][ni] = __builtin_amdgcn_mfma_f32_16x16x32_bf16(
              af[mi], bfr[ni], acc[mi][ni], 0, 0, 0);
    }
  }

  const int lrg = (lane >> 4) * 4;
  unsigned long long fbm = 0;
#pragma unroll
  for (int mi = 0; mi < 4; ++mi)
#pragma unroll
    for (int r = 0; r < 4; ++r) {
      const int o = o0 + wr + mi * 16 + lrg + r;
      const float inv = gamma[o] / sqrtf(var[o] + BN_EPS);
      const float bias = beta[o] - mean[o] * inv;
#pragma unroll
      for (int ni = 0; ni < 4; ++ni) {
        int tt = t0 + wc + ni * 16 + lrow;
        float y = acc[mi][ni][r] * inv + bias;
        if (fabsf(y - THRESH) < 0.02f) fbm |= 1ull << (mi * 16 + ni * 4 + r);
        float s = (y >= THRESH) ? 1.0f : 0.0f;
        float4 sv = make_float4(s, s, s, s);
        float* dp = out + ((size_t)b * 512 + o) * 4096 + (size_t)tt * 8;
        ((float4*)dp)[0] = sv;
        ((float4*)dp)[1] = sv;
      }
    }
  if (__builtin_expect(fbm != 0, 0)) {  // exact fp32 recompute, ~never taken
    for (int bit = 0; bit < 64; ++bit) {
      if (!((fbm >> bit) & 1)) continue;
      int mi = bit >> 4, ni = (bit >> 2) & 3, r = bit & 3;
      int o = o0 + wr + mi * 16 + lrg + r;
      int tt = t0 + wc + ni * 16 + lrow;
      const float* wrow = Wf + (size_t)o * 512;
      const float* arow = attT + ((size_t)b * 512 + tt) * 512;
      float s = 0.f;
      for (int c = 0; c < 512; ++c) s += wrow[c] * arow[c];
      float inv = gamma[o] / sqrtf(var[o] + BN_EPS);
      float y = s * inv + (beta[o] - mean[o] * inv);
      float sp = (y >= THRESH) ? 1.0f : 0.0f;
      float4 sv = make_float4(sp, sp, sp, sp);
      float* dp = out + ((size_t)b * 512 + o) * 4096 + (size_t)tt * 8;
      ((float4*)dp)[0] = sv;
      ((float4*)dp)[1] = sv;
    }
  }
}

extern "C" void kernel_launch(void* const* d_in, const int* in_sizes, int n_in,
                              void* d_out, int out_size, void* d_ws, size_t ws_size,
                              hipStream_t stream) {
  (void)in_sizes; (void)n_in; (void)out_size; (void)ws_size;
  const float* x     = (const float*)d_in[0];
  const float* w_qkv = (const float*)d_in[1];
  const float* w_out = (const float*)d_in[2];
  const float* gamma = (const float*)d_in[3];
  const float* beta  = (const float*)d_in[4];
  const float* mean  = (const float*)d_in[5];
  const float* var   = (const float*)d_in[6];
  float* outp = (float*)d_out;

  // d_out-front scratch: consumed BEFORE out_gemm writes d_out.
  //   [0,16MB)   xpT  bf16 (32,512t,512c)
  //   [16,64MB)  qkvb bf16 (32,1536,512)
  // d_ws scratch (out_gemm inputs must NOT alias d_out):
  //   [0,32MB)   attT  f32  (32,512t,512c)
  //   [32,48MB)  attTb bf16 (32,512t,512c)
  //   [48,..)    Wqb bf16, [50MB) Wob bf16, [51MB) flags int[32]
  char* ob = (char*)d_out;
  char* wb = (char*)d_ws;
  short* xpT  = (short*)(ob);
  short* qkvb = (short*)(ob + ((size_t)16 << 20));
  float* attT  = (float*)(wb);
  short* attTb = (short*)(wb + ((size_t)32 << 20));
  short* Wqb   = (short*)(wb + ((size_t)48 << 20));
  short* Wob   = (short*)(wb + ((size_t)50 << 20));
  int*   flags = (int*)(wb + ((size_t)51 << 20));

  wconv_kernel<<<1024, 256, 0, stream>>>(w_qkv, w_out, Wqb, Wob, flags);
  pool_t_kernel<<<dim3(8, 8, 32), 256, 0, stream>>>(x, xpT);
  qkv_gemm_mfma<<<dim3(4, 12, 32), 256, 0, stream>>>(Wqb, xpT, w_qkv, x, qkvb,
                                                     flags);
  attn_kernel<<<dim3(2, 8, 32), 256, 0, stream>>>(qkvb, attT, attTb, flags);
  out_gemm_mfma<<<dim3(4, 4, 32), 256, 0, stream>>>(Wob, attTb, w_out, attT,
                                                    gamma, beta, mean, var,
                                                    outp, flags);
}